// Round 1
// baseline (288.847 us; speedup 1.0000x reference)
//
#include <hip/hip_runtime.h>
#include <stdint.h>

#define HEADS 16
#define HD    64
#define SEQ   2048
#define BATCH 2
#define EMB   1024

using short8  = __attribute__((ext_vector_type(8))) short;
using float4v = __attribute__((ext_vector_type(4))) float;

__device__ __forceinline__ unsigned int f2bfraw(float f) {
    unsigned int u = __float_as_uint(f);
    return (u + 0x7fffu + ((u >> 16) & 1u)) >> 16;
}

// ---------------- Wo fp32 -> bf16 ----------------
__global__ __launch_bounds__(256) void cvt_wo_kernel(const float* __restrict__ Wo,
                                                     unsigned short* __restrict__ Wob) {
    int i = (blockIdx.x * 256 + threadIdx.x) * 4;
    float4 v = *(const float4*)(Wo + i);
    uint2 o;
    o.x = f2bfraw(v.x) | (f2bfraw(v.y) << 16);
    o.y = f2bfraw(v.z) | (f2bfraw(v.w) << 16);
    *(uint2*)(Wob + i) = o;
}

// ---------------- QKV projection ----------------
// out[b,s,h,e] = sum_d x[b,s,h*64+d] * W[e,d]
// z=0: queries->Qp (B,H,S,D)   z=1: keys->Kp (B,H,S,D)   z=2: values->Vt (B,H,D,S)
__global__ __launch_bounds__(256) void proj_kernel(
    const float* __restrict__ Vx, const float* __restrict__ Kx, const float* __restrict__ Qx,
    const float* __restrict__ Wv, const float* __restrict__ Wk, const float* __restrict__ Wq,
    unsigned short* __restrict__ Qp, unsigned short* __restrict__ Kp,
    unsigned short* __restrict__ Vt) {
    __shared__ __align__(16) float Wt[64 * 68];           // Wt[d][e]
    __shared__ __align__(16) float xs[64 * 68];           // xs[s][d]
    __shared__ __align__(16) unsigned short vt[64 * 72];  // vt[e][s] (v path)

    const int t  = threadIdx.x;
    const int z  = blockIdx.z;
    const int bh = blockIdx.y;
    const int b  = bh >> 4, h = bh & 15;
    const int s0 = blockIdx.x * 64;

    const float* x = (z == 0) ? Qx : (z == 1) ? Kx : Vx;
    const float* W = (z == 0) ? Wq : (z == 1) ? Wk : Wv;

    // stage W transposed: Wt[d][e] = W[e][d]
#pragma unroll
    for (int rep = 0; rep < 4; ++rep) {
        int idx = rep * 1024 + t * 4;
        int e = idx >> 6, d0 = idx & 63;
        float4 w4 = *(const float4*)(W + idx);
        Wt[(d0 + 0) * 68 + e] = w4.x;
        Wt[(d0 + 1) * 68 + e] = w4.y;
        Wt[(d0 + 2) * 68 + e] = w4.z;
        Wt[(d0 + 3) * 68 + e] = w4.w;
    }
    // stage x tile: xs[s][d] = x[b, s0+s, h*64+d]
#pragma unroll
    for (int rep = 0; rep < 4; ++rep) {
        int idx = rep * 1024 + t * 4;
        int s = idx >> 6, d0 = idx & 63;
        float4 v4 = *(const float4*)(x + (size_t)(b * SEQ + s0 + s) * EMB + h * 64 + d0);
        *(float4*)(&xs[s * 68 + d0]) = v4;
    }
    __syncthreads();

    const int sl = t >> 2;
    const int e0 = (t & 3) * 16;
    float acc[16];
#pragma unroll
    for (int i = 0; i < 16; ++i) acc[i] = 0.f;
#pragma unroll 8
    for (int d = 0; d < 64; ++d) {
        float xv = xs[sl * 68 + d];
        float4 w0 = *(const float4*)(&Wt[d * 68 + e0]);
        float4 w1 = *(const float4*)(&Wt[d * 68 + e0 + 4]);
        float4 w2 = *(const float4*)(&Wt[d * 68 + e0 + 8]);
        float4 w3 = *(const float4*)(&Wt[d * 68 + e0 + 12]);
        acc[0] += xv * w0.x;  acc[1] += xv * w0.y;  acc[2] += xv * w0.z;  acc[3] += xv * w0.w;
        acc[4] += xv * w1.x;  acc[5] += xv * w1.y;  acc[6] += xv * w1.z;  acc[7] += xv * w1.w;
        acc[8] += xv * w2.x;  acc[9] += xv * w2.y;  acc[10] += xv * w2.z; acc[11] += xv * w2.w;
        acc[12] += xv * w3.x; acc[13] += xv * w3.y; acc[14] += xv * w3.z; acc[15] += xv * w3.w;
    }

    if (z < 2) {
        unsigned short* outp = (z == 0) ? Qp : Kp;
        size_t base = ((size_t)bh * SEQ + s0 + sl) * 64 + e0;
        unsigned int pk[8];
#pragma unroll
        for (int i = 0; i < 8; ++i)
            pk[i] = f2bfraw(acc[2 * i]) | (f2bfraw(acc[2 * i + 1]) << 16);
        *(uint4*)(outp + base)     = make_uint4(pk[0], pk[1], pk[2], pk[3]);
        *(uint4*)(outp + base + 8) = make_uint4(pk[4], pk[5], pk[6], pk[7]);
    } else {
        // transpose within tile via LDS, then coalesced store to (B,H,D,S)
#pragma unroll
        for (int i = 0; i < 16; ++i)
            vt[(e0 + i) * 72 + sl] = (unsigned short)f2bfraw(acc[i]);
        __syncthreads();
        int e = t >> 2;
        int sc0 = (t & 3) * 16;
        uint4 a = *(const uint4*)(&vt[e * 72 + sc0]);
        uint4 c = *(const uint4*)(&vt[e * 72 + sc0 + 8]);
        size_t base = ((size_t)bh * 64 + e) * SEQ + s0 + sc0;
        *(uint4*)(Vt + base)     = a;
        *(uint4*)(Vt + base + 8) = c;
    }
}

// ---------------- flash attention ----------------
// Qp,Kp: (B,H,S,D) bf16; Vt: (B,H,D,S) bf16; AO out: (B,H,S,D) bf16
__global__ __launch_bounds__(256) void attn_kernel(
    const unsigned short* __restrict__ Qp, const unsigned short* __restrict__ Kp,
    const unsigned short* __restrict__ Vt, unsigned short* __restrict__ AO) {
    __shared__ __align__(16) unsigned short Ks[64 * 72];      // [key][d]
    __shared__ __align__(16) unsigned short Vs[64 * 72];      // [d][key]
    __shared__ __align__(16) unsigned short Ps[4][16 * 72];   // per-wave [qrow][key]

    const int t = threadIdx.x;
    const int w = t >> 6, lane = t & 63, cl = lane & 15, quad = lane >> 4;
    const int bh = blockIdx.y;
    const int q0 = blockIdx.x * 64;
    const size_t hbase = (size_t)bh * SEQ * 64;

    // Q fragments stay in registers: A[m=cl][k = 32*s2 + quad*8 + j]
    short8 aq0, aq1;
    {
        size_t rbase = hbase + (size_t)(q0 + w * 16 + cl) * 64 + quad * 8;
        aq0 = *(const short8*)(Qp + rbase);
        aq1 = *(const short8*)(Qp + rbase + 32);
    }

    float4v acc[4];
#pragma unroll
    for (int nt = 0; nt < 4; ++nt) acc[nt] = (float4v){0.f, 0.f, 0.f, 0.f};
    float m[4], l[4];
#pragma unroll
    for (int r = 0; r < 4; ++r) { m[r] = -1e30f; l[r] = 0.f; }

    for (int kc = 0; kc < SEQ / 64; ++kc) {
        // stage K chunk [key][d] and V chunk [d][key]
#pragma unroll
        for (int p = 0; p < 2; ++p) {
            int idx = t * 8 + p * 2048;
            int row = idx >> 6, col0 = idx & 63;
            uint4 kv = *(const uint4*)(Kp + hbase + (size_t)kc * 4096 + idx);
            *(uint4*)(&Ks[row * 72 + col0]) = kv;
            uint4 vv = *(const uint4*)(Vt + hbase + (size_t)row * SEQ + kc * 64 + col0);
            *(uint4*)(&Vs[row * 72 + col0]) = vv;
        }
        __syncthreads();

        // scores: D[m=qrow][n=key] = Q * K^T
        float4v c[4];
#pragma unroll
        for (int nt = 0; nt < 4; ++nt) c[nt] = (float4v){0.f, 0.f, 0.f, 0.f};
#pragma unroll
        for (int nt = 0; nt < 4; ++nt) {
            short8 bk0 = *(const short8*)(&Ks[(nt * 16 + cl) * 72 + quad * 8]);
            c[nt] = __builtin_amdgcn_mfma_f32_16x16x32_bf16(aq0, bk0, c[nt], 0, 0, 0);
            short8 bk1 = *(const short8*)(&Ks[(nt * 16 + cl) * 72 + 32 + quad * 8]);
            c[nt] = __builtin_amdgcn_mfma_f32_16x16x32_bf16(aq1, bk1, c[nt], 0, 0, 0);
        }

        // online softmax per row (row = quad*4 + r, replicated over 16 lanes)
#pragma unroll
        for (int r = 0; r < 4; ++r) {
            float s0 = c[0][r] * 0.125f, s1 = c[1][r] * 0.125f;
            float s2 = c[2][r] * 0.125f, s3 = c[3][r] * 0.125f;
            float pm = fmaxf(fmaxf(s0, s1), fmaxf(s2, s3));
            pm = fmaxf(pm, __shfl_xor(pm, 1));
            pm = fmaxf(pm, __shfl_xor(pm, 2));
            pm = fmaxf(pm, __shfl_xor(pm, 4));
            pm = fmaxf(pm, __shfl_xor(pm, 8));
            float mnew  = fmaxf(m[r], pm);
            float alpha = __expf(m[r] - mnew);
            float p0 = __expf(s0 - mnew), p1 = __expf(s1 - mnew);
            float p2 = __expf(s2 - mnew), p3 = __expf(s3 - mnew);
            int prow = (quad * 4 + r) * 72;
            Ps[w][prow + cl]      = (unsigned short)f2bfraw(p0);
            Ps[w][prow + 16 + cl] = (unsigned short)f2bfraw(p1);
            Ps[w][prow + 32 + cl] = (unsigned short)f2bfraw(p2);
            Ps[w][prow + 48 + cl] = (unsigned short)f2bfraw(p3);
            float ps = p0 + p1 + p2 + p3;
            ps += __shfl_xor(ps, 1);
            ps += __shfl_xor(ps, 2);
            ps += __shfl_xor(ps, 4);
            ps += __shfl_xor(ps, 8);
            l[r] = l[r] * alpha + ps;
            m[r] = mnew;
            acc[0][r] *= alpha; acc[1][r] *= alpha;
            acc[2][r] *= alpha; acc[3][r] *= alpha;
        }
        __syncthreads();  // Ps visibility (C-layout -> A-layout round trip)

        // O += P * V
#pragma unroll
        for (int s2i = 0; s2i < 2; ++s2i) {
            short8 ap = *(const short8*)(&Ps[w][cl * 72 + s2i * 32 + quad * 8]);
#pragma unroll
            for (int nt = 0; nt < 4; ++nt) {
                short8 bv = *(const short8*)(&Vs[(nt * 16 + cl) * 72 + s2i * 32 + quad * 8]);
                acc[nt] = __builtin_amdgcn_mfma_f32_16x16x32_bf16(ap, bv, acc[nt], 0, 0, 0);
            }
        }
        __syncthreads();  // protect Ks/Vs before next staging
    }

    float inv[4];
#pragma unroll
    for (int r = 0; r < 4; ++r) inv[r] = 1.0f / l[r];
#pragma unroll
    for (int nt = 0; nt < 4; ++nt) {
#pragma unroll
        for (int r = 0; r < 4; ++r) {
            int row = q0 + w * 16 + quad * 4 + r;
            AO[hbase + (size_t)row * 64 + nt * 16 + cl] =
                (unsigned short)f2bfraw(acc[nt][r] * inv[r]);
        }
    }
}

// ---------------- output projection: out = AO @ Wo^T + bo ----------------
// AO: (B,H,S,D) bf16 viewed as M=4096 rows, K=1024 (k = h*64+d); Wob: [e][k] bf16
__global__ __launch_bounds__(256) void outproj_kernel(
    const unsigned short* __restrict__ AO, const unsigned short* __restrict__ Wob,
    const float* __restrict__ bo, float* __restrict__ out) {
    __shared__ __align__(16) unsigned short As[64 * 72];
    __shared__ __align__(16) unsigned short Bs[64 * 72];

    const int t = threadIdx.x, w = t >> 6, lane = t & 63, cl = lane & 15, quad = lane >> 4;
    const int e0 = blockIdx.x * 64;
    const int m0 = blockIdx.y * 64;

    float4v c[4];
#pragma unroll
    for (int nt = 0; nt < 4; ++nt) c[nt] = (float4v){0.f, 0.f, 0.f, 0.f};

    for (int hc = 0; hc < 16; ++hc) {
#pragma unroll
        for (int p = 0; p < 2; ++p) {
            int idx = t * 8 + p * 2048;
            int i = idx >> 6, d0 = idx & 63;
            int r = m0 + i;
            int b = r >> 11, s = r & 2047;
            uint4 av = *(const uint4*)(AO + ((size_t)(b * 16 + hc) * SEQ + s) * 64 + d0);
            *(uint4*)(&As[i * 72 + d0]) = av;
            uint4 bv = *(const uint4*)(Wob + (size_t)(e0 + i) * EMB + hc * 64 + d0);
            *(uint4*)(&Bs[i * 72 + d0]) = bv;
        }
        __syncthreads();
#pragma unroll
        for (int s2i = 0; s2i < 2; ++s2i) {
            short8 a = *(const short8*)(&As[(w * 16 + cl) * 72 + s2i * 32 + quad * 8]);
#pragma unroll
            for (int nt = 0; nt < 4; ++nt) {
                short8 bb = *(const short8*)(&Bs[(nt * 16 + cl) * 72 + s2i * 32 + quad * 8]);
                c[nt] = __builtin_amdgcn_mfma_f32_16x16x32_bf16(a, bb, c[nt], 0, 0, 0);
            }
        }
        __syncthreads();
    }

#pragma unroll
    for (int nt = 0; nt < 4; ++nt) {
        float bias = bo[e0 + nt * 16 + cl];
#pragma unroll
        for (int r = 0; r < 4; ++r) {
            int row = m0 + w * 16 + quad * 4 + r;
            out[(size_t)row * EMB + e0 + nt * 16 + cl] = c[nt][r] + bias;
        }
    }
}

extern "C" void kernel_launch(void* const* d_in, const int* in_sizes, int n_in,
                              void* d_out, int out_size, void* d_ws, size_t ws_size,
                              hipStream_t stream) {
    const float* values  = (const float*)d_in[0];
    const float* keys    = (const float*)d_in[1];
    const float* queries = (const float*)d_in[2];
    const float* Wv = (const float*)d_in[3];
    const float* Wk = (const float*)d_in[4];
    const float* Wq = (const float*)d_in[5];
    const float* Wo = (const float*)d_in[6];
    const float* bo = (const float*)d_in[7];
    float* out = (float*)d_out;

    char* ws = (char*)d_ws;
    unsigned short* Qp  = (unsigned short*)(ws);                    // 8 MB (B,H,S,D)
    unsigned short* Kp  = (unsigned short*)(ws + (8u  << 20));      // 8 MB (B,H,S,D)
    unsigned short* Vt  = (unsigned short*)(ws + (16u << 20));      // 8 MB (B,H,D,S)
    unsigned short* AO  = (unsigned short*)(ws + (24u << 20));      // 8 MB (B,H,S,D)
    unsigned short* Wob = (unsigned short*)(ws + (32u << 20));      // 2 MB [e][k]

    cvt_wo_kernel<<<dim3(1024), dim3(256), 0, stream>>>(Wo, Wob);
    proj_kernel<<<dim3(SEQ / 64, BATCH * HEADS, 3), dim3(256), 0, stream>>>(
        values, keys, queries, Wv, Wk, Wq, Qp, Kp, Vt);
    attn_kernel<<<dim3(SEQ / 64, BATCH * HEADS), dim3(256), 0, stream>>>(Qp, Kp, Vt, AO);
    outproj_kernel<<<dim3(EMB / 64, (BATCH * SEQ) / 64), dim3(256), 0, stream>>>(
        AO, Wob, bo, out);
}